// Round 9
// baseline (292.305 us; speedup 1.0000x reference)
//
#include <hip/hip_runtime.h>
#include <hip/hip_bf16.h>
#include <math.h>

#define SLOPE 0.2f

typedef __attribute__((ext_vector_type(8))) short short8;
typedef __attribute__((ext_vector_type(4))) float f32x4;
typedef __attribute__((ext_vector_type(4))) int   i32x4;

static __device__ __forceinline__ float leakyf(float x) { return x >= 0.f ? x : SLOPE * x; }
static __device__ __forceinline__ float bflo(unsigned u) { return __builtin_bit_cast(float, u << 16); }
static __device__ __forceinline__ float bfhi(unsigned u) { return __builtin_bit_cast(float, u & 0xffff0000u); }
static __device__ __forceinline__ unsigned short f2bf(float f) {
    unsigned u = __builtin_bit_cast(unsigned, f);
    return (unsigned short)((u + 0x7fff + ((u >> 16) & 1)) >> 16);  // RNE
}

struct __align__(8) us4 { unsigned short a, b, c, d; };

// Permuted within-head column layout: slot p (in [0,64) of a head block) holds true
// column c64(p) = (p&3)*16 + (p>>2).  Inverse: p(c) = (c&15)*4 + (c>>4).

// ---------------- prep: fused weight transpose/convert/K-permute + zero hist counts ------
__global__ __launch_bounds__(256) void prep(const float* __restrict__ W1,
                                            const float* __restrict__ W2,
                                            const float* __restrict__ W3,
                                            const float* __restrict__ rW3,
                                            unsigned short* __restrict__ W1t,
                                            unsigned short* __restrict__ W2t,
                                            unsigned short* __restrict__ W3c,
                                            int* __restrict__ counts, int n) {
    int b = blockIdx.x;
    if (b < 512) {
        int i = b * 256 + threadIdx.x;
        const float* W; unsigned short* Wt; int K, lNc, idx; bool permK;
        if (i < 32768)       { W = W1;  Wt = W1t;            K = 128; lNc = 8; idx = i;          permK = false; }
        else if (i < 98304)  { W = W2;  Wt = W2t;            K = 256; lNc = 8; idx = i - 32768;  permK = true; }
        else if (i < 114688) { W = W3;  Wt = W3c;            K = 256; lNc = 6; idx = i - 98304;  permK = true; }
        else                 { W = rW3; Wt = W3c + 64 * 256; K = 256; lNc = 6; idx = i - 114688; permK = true; }
        int k = idx >> lNc, nn = idx & ((1 << lNc) - 1);
        int kp = permK ? ((k & ~63) | (((k & 15) << 2) | ((k & 63) >> 4))) : k;
        Wt[nn * K + kp] = f2bf(W[idx]);
    } else {
        int idx = (b - 512) * 256 + threadIdx.x;
        if (idx < n) counts[idx] = 0;
    }
}

// ---------------- MFMA GEMM (layers 1/2) + fused attention projections -------------------
template<bool A_F32>
__global__ __launch_bounds__(256) void gemm_l12(const void* __restrict__ Av,
                                                const unsigned short* __restrict__ Wt,
                                                unsigned short* __restrict__ outb,
                                                const float* __restrict__ al,
                                                const float* __restrict__ ar,
                                                float* __restrict__ el,
                                                float* __restrict__ er,
                                                int M, int K) {
    const int lane = threadIdx.x & 63;
    const int wid = threadIdx.x >> 6;       // head
    const int rlo = lane & 15;
    const int q = lane >> 4;
    const int kg = q * 8;
    const int m0 = blockIdx.x * 64;
    const int cbase = wid * 64;

    f32x4 acc[4][4];
#pragma unroll
    for (int mf = 0; mf < 4; ++mf)
#pragma unroll
        for (int nf = 0; nf < 4; ++nf) acc[mf][nf] = (f32x4){0.f, 0.f, 0.f, 0.f};

    for (int k0 = 0; k0 < K; k0 += 32) {
        short8 a[4];
#pragma unroll
        for (int mf = 0; mf < 4; ++mf) {
            int r = m0 + mf * 16 + rlo;
            if (r >= M) r = M - 1;  // clamp; affects only unstored rows
            if (A_F32) {
                const float* ap = (const float*)Av + (size_t)r * K + k0 + kg;
                float4 f0 = *(const float4*)ap;
                float4 f1 = *(const float4*)(ap + 4);
                short8 t;
                t[0] = f2bf(f0.x); t[1] = f2bf(f0.y); t[2] = f2bf(f0.z); t[3] = f2bf(f0.w);
                t[4] = f2bf(f1.x); t[5] = f2bf(f1.y); t[6] = f2bf(f1.z); t[7] = f2bf(f1.w);
                a[mf] = t;
            } else {
                a[mf] = *(const short8*)((const unsigned short*)Av + (size_t)r * K + k0 + kg);
            }
        }
#pragma unroll
        for (int nf = 0; nf < 4; ++nf) {
            short8 b = *(const short8*)(Wt + (size_t)(cbase + nf * 16 + rlo) * K + k0 + kg);
#pragma unroll
            for (int mf = 0; mf < 4; ++mf)
                acc[mf][nf] = __builtin_amdgcn_mfma_f32_16x16x32_bf16(a[mf], b, acc[mf][nf], 0, 0, 0);
        }
    }

    float alv[4], arv[4];
#pragma unroll
    for (int nf = 0; nf < 4; ++nf) {
        alv[nf] = al[cbase + nf * 16 + rlo];
        arv[nf] = ar[cbase + nf * 16 + rlo];
    }

#pragma unroll
    for (int mf = 0; mf < 4; ++mf) {
#pragma unroll
        for (int reg = 0; reg < 4; ++reg) {
            int r = m0 + mf * 16 + q * 4 + reg;
            float pl = 0.f, pr = 0.f;
#pragma unroll
            for (int nf = 0; nf < 4; ++nf) {
                pl += acc[mf][nf][reg] * alv[nf];
                pr += acc[mf][nf][reg] * arv[nf];
            }
#pragma unroll
            for (int off = 1; off < 16; off <<= 1) {
                pl += __shfl_xor(pl, off);
                pr += __shfl_xor(pr, off);
            }
            if (rlo == 0 && r < M) {
                el[(size_t)r * 4 + wid] = pl;
                er[(size_t)r * 4 + wid] = pr;
            }
            if (r < M) {
                us4 o = {f2bf(acc[mf][0][reg]), f2bf(acc[mf][1][reg]),
                         f2bf(acc[mf][2][reg]), f2bf(acc[mf][3][reg])};
                *(us4*)(outb + (size_t)r * 256 + cbase + rlo * 4) = o;  // permuted slots
            }
        }
    }
}

// ---------------- layer-3 fused GEMM: h2(perm) @ [W3 | res_W3] ---------------------------
__global__ __launch_bounds__(256) void gemm_l3(const unsigned short* __restrict__ A,
                                               const unsigned short* __restrict__ Wt,
                                               unsigned short* __restrict__ featb,
                                               float* __restrict__ resf,
                                               const float* __restrict__ al,
                                               const float* __restrict__ ar,
                                               float* __restrict__ el,
                                               float* __restrict__ er, int M) {
    const int K = 256;
    const int lane = threadIdx.x & 63;
    const int wid = threadIdx.x >> 6;
    const int rlo = lane & 15;
    const int q = lane >> 4;
    const int kg = q * 8;
    const int m0 = blockIdx.x * 128 + (wid >> 1) * 64;
    const int ch = wid & 1;
    const int cbase = ch * 64;

    f32x4 acc[4][4];
#pragma unroll
    for (int mf = 0; mf < 4; ++mf)
#pragma unroll
        for (int nf = 0; nf < 4; ++nf) acc[mf][nf] = (f32x4){0.f, 0.f, 0.f, 0.f};

    for (int k0 = 0; k0 < K; k0 += 32) {
        short8 a[4];
#pragma unroll
        for (int mf = 0; mf < 4; ++mf) {
            int r = m0 + mf * 16 + rlo;
            if (r >= M) r = M - 1;
            a[mf] = *(const short8*)(A + (size_t)r * K + k0 + kg);
        }
#pragma unroll
        for (int nf = 0; nf < 4; ++nf) {
            short8 b = *(const short8*)(Wt + (size_t)(cbase + nf * 16 + rlo) * K + k0 + kg);
#pragma unroll
            for (int mf = 0; mf < 4; ++mf)
                acc[mf][nf] = __builtin_amdgcn_mfma_f32_16x16x32_bf16(a[mf], b, acc[mf][nf], 0, 0, 0);
        }
    }

    float alv[4], arv[4];
    if (ch == 0) {
#pragma unroll
        for (int nf = 0; nf < 4; ++nf) {
            alv[nf] = al[nf * 16 + rlo];
            arv[nf] = ar[nf * 16 + rlo];
        }
    }

#pragma unroll
    for (int mf = 0; mf < 4; ++mf) {
#pragma unroll
        for (int reg = 0; reg < 4; ++reg) {
            int r = m0 + mf * 16 + q * 4 + reg;
            if (ch == 0) {
                float pl = 0.f, pr = 0.f;
#pragma unroll
                for (int nf = 0; nf < 4; ++nf) {
                    pl += acc[mf][nf][reg] * alv[nf];
                    pr += acc[mf][nf][reg] * arv[nf];
                }
#pragma unroll
                for (int off = 1; off < 16; off <<= 1) {
                    pl += __shfl_xor(pl, off);
                    pr += __shfl_xor(pr, off);
                }
                if (rlo == 0 && r < M) { el[r] = pl; er[r] = pr; }
                if (r < M) {
                    us4 o = {f2bf(acc[mf][0][reg]), f2bf(acc[mf][1][reg]),
                             f2bf(acc[mf][2][reg]), f2bf(acc[mf][3][reg])};
                    *(us4*)(featb + (size_t)r * 64 + rlo * 4) = o;  // permuted
                }
            } else if (r < M) {
                float4 o = {acc[mf][0][reg], acc[mf][1][reg], acc[mf][2][reg], acc[mf][3][reg]};
                *(float4*)(resf + (size_t)r * 64 + rlo * 4) = o;    // permuted
            }
        }
    }
}

// ---------------- CSR build --------------------------------------------------------------
__global__ void hist_kernel(const int* __restrict__ dst, int* __restrict__ counts, int e) {
    int i = blockIdx.x * blockDim.x + threadIdx.x;
    if (i < e) atomicAdd(&counts[dst[i]], 1);
}

__global__ __launch_bounds__(1024) void scan_block(const int* __restrict__ counts,
                                                   int* __restrict__ offsets,
                                                   int* __restrict__ bsums, int n) {
    __shared__ int ws[16];
    int tid = threadIdx.x, lane = tid & 63, wid = tid >> 6;
    int idx = blockIdx.x * 1024 + tid;
    int v = (idx < n) ? counts[idx] : 0;
    int s = v;
#pragma unroll
    for (int off = 1; off < 64; off <<= 1) {
        int t = __shfl_up(s, off);
        if (lane >= off) s += t;
    }
    if (lane == 63) ws[wid] = s;
    __syncthreads();
    if (tid < 16) {
        int w2 = ws[tid];
#pragma unroll
        for (int off = 1; off < 16; off <<= 1) {
            int t = __shfl_up(w2, off);
            if (tid >= off) w2 += t;
        }
        ws[tid] = w2;
    }
    __syncthreads();
    int wpre = wid ? ws[wid - 1] : 0;
    if (idx < n) offsets[idx] = wpre + s - v;
    if (tid == 0) bsums[blockIdx.x] = ws[15];
}

__global__ __launch_bounds__(1024) void add_off(const int* __restrict__ bsums,
                                                int* __restrict__ offsets,
                                                int* __restrict__ cursor, int n, int e, int nb) {
    __shared__ int base_s;
    int tid = threadIdx.x;
    if (tid < 64) {
        int v = (tid < blockIdx.x && tid < nb) ? bsums[tid] : 0;
#pragma unroll
        for (int off = 32; off > 0; off >>= 1) v += __shfl_xor(v, off);
        if (tid == 0) base_s = v;
    }
    __syncthreads();
    int idx = blockIdx.x * 1024 + tid;
    if (idx < n) {
        int v = offsets[idx] + base_s;
        offsets[idx] = v;
        cursor[idx] = v;
    }
    if (idx == 0) offsets[n] = e;
}

__global__ void scatter_kernel(const int* __restrict__ src, const int* __restrict__ dst,
                               int* __restrict__ cursor, int* __restrict__ csr_src, int e) {
    int i = blockIdx.x * blockDim.x + threadIdx.x;
    if (i < e) {
        int pos = atomicAdd(&cursor[dst[i]], 1);
        csr_src[pos] = src[i];
    }
}

// ---------------- H=4 aggregate: 2 nodes/wave, inline scores, 16B/lane gathers ------------
// half = lane>>5 -> node; sub = lane&31 owns permuted slots [sub*8,+8); head = sub>>3.
// RES: 0 none, 1 bf16 resid (permuted). ACT: 1 = elu.
template<int RES, int ACT>
__global__ __launch_bounds__(256) void gat_agg4(const unsigned short* __restrict__ fp,
                                                const float* __restrict__ el,
                                                const float* __restrict__ er,
                                                const int* __restrict__ offsets,
                                                const int* __restrict__ csr_src,
                                                const unsigned short* __restrict__ resid,
                                                unsigned short* __restrict__ outb, int n) {
    int wv = threadIdx.x >> 6;
    int lane = threadIdx.x & 63;
    int half = lane >> 5;
    int sub = lane & 31;
    int node = blockIdx.x * 8 + wv * 2 + half;

    int e0 = 0, e1 = 0;
    if (node < n) { e0 = offsets[node]; e1 = offsets[node + 1]; }
    int cnt = e1 - e0;
    int ocnt = __shfl_xor(cnt, 32);
    int mc = cnt > ocnt ? cnt : ocnt;

    const int hd = sub >> 3;
    float erh = (node < n) ? er[(size_t)node * 4 + hd] : 0.f;

    float den = 0.f;
    float acc[8] = {0.f, 0.f, 0.f, 0.f, 0.f, 0.f, 0.f, 0.f};

    for (int t = 0; t < mc; t += 8) {
        i32x4 sv0, sv1;
        __builtin_memcpy(&sv0, csr_src + e0 + t, 16);      // overreads stay inside d_ws pad
        __builtin_memcpy(&sv1, csr_src + e0 + t + 4, 16);
        int s[8];
        float msk[8];
#pragma unroll
        for (int j = 0; j < 8; ++j) {
            bool ok = (t + j) < cnt;
            s[j] = ok ? ((j < 4) ? sv0[j] : sv1[j - 4]) : 0;
            msk[j] = ok ? 1.f : 0.f;
        }
        // issue the 512B-row gathers first (independent, max MLP)
        uint4 u[8];
#pragma unroll
        for (int j = 0; j < 8; ++j)
            u[j] = *(const uint4*)(fp + (size_t)s[j] * 256 + sub * 8);
        // inline scores: el table is 800KB -> L2-resident gathers
        float w[8];
#pragma unroll
        for (int j = 0; j < 8; ++j) {
            float xx = fminf(leakyf(el[(size_t)s[j] * 4 + hd] + erh), 80.f);
            w[j] = msk[j] * __expf(xx);
        }
#pragma unroll
        for (int j = 0; j < 8; ++j) {
            den += w[j];
            acc[0] += w[j] * bflo(u[j].x);
            acc[1] += w[j] * bfhi(u[j].x);
            acc[2] += w[j] * bflo(u[j].y);
            acc[3] += w[j] * bfhi(u[j].y);
            acc[4] += w[j] * bflo(u[j].z);
            acc[5] += w[j] * bfhi(u[j].z);
            acc[6] += w[j] * bflo(u[j].w);
            acc[7] += w[j] * bfhi(u[j].w);
        }
    }

    if (node >= n) return;

    float inv = den > 0.f ? 1.f / den : 0.f;
    float v[8];
#pragma unroll
    for (int i = 0; i < 8; ++i) v[i] = acc[i] * inv;

    if (RES == 1) {
        uint4 ru = *(const uint4*)(resid + (size_t)node * 256 + sub * 8);
        v[0] += bflo(ru.x); v[1] += bfhi(ru.x);
        v[2] += bflo(ru.y); v[3] += bfhi(ru.y);
        v[4] += bflo(ru.z); v[5] += bfhi(ru.z);
        v[6] += bflo(ru.w); v[7] += bfhi(ru.w);
    }
    if (ACT == 1) {
#pragma unroll
        for (int i = 0; i < 8; ++i) v[i] = v[i] > 0.f ? v[i] : __expf(v[i]) - 1.f;
    }
    uint4 o;
    o.x = (unsigned)f2bf(v[0]) | ((unsigned)f2bf(v[1]) << 16);
    o.y = (unsigned)f2bf(v[2]) | ((unsigned)f2bf(v[3]) << 16);
    o.z = (unsigned)f2bf(v[4]) | ((unsigned)f2bf(v[5]) << 16);
    o.w = (unsigned)f2bf(v[6]) | ((unsigned)f2bf(v[7]) << 16);
    *(uint4*)(outb + (size_t)node * 256 + sub * 8) = o;
}

// ---------------- H=1 aggregate: 4 nodes/wave, inline scores, 8B/lane gathers -------------
__global__ __launch_bounds__(256) void gat_agg1(const unsigned short* __restrict__ fp,
                                                const float* __restrict__ el,
                                                const float* __restrict__ er,
                                                const int* __restrict__ offsets,
                                                const int* __restrict__ csr_src,
                                                const float* __restrict__ resf,
                                                float* __restrict__ outv, int n) {
    int wv = threadIdx.x >> 6;
    int lane = threadIdx.x & 63;
    int sub = lane & 15;
    int node = blockIdx.x * 16 + wv * 4 + (lane >> 4);

    int e0 = 0, e1 = 0;
    if (node < n) { e0 = offsets[node]; e1 = offsets[node + 1]; }
    int cnt = e1 - e0;
    int m1 = __shfl_xor(cnt, 16);
    int mc = cnt > m1 ? cnt : m1;
    int m2 = __shfl_xor(mc, 32);
    mc = mc > m2 ? mc : m2;

    float ern = (node < n) ? er[node] : 0.f;

    float den = 0.f;
    float acc[4] = {0.f, 0.f, 0.f, 0.f};

    for (int t = 0; t < mc; t += 8) {
        i32x4 sv0, sv1;
        __builtin_memcpy(&sv0, csr_src + e0 + t, 16);
        __builtin_memcpy(&sv1, csr_src + e0 + t + 4, 16);
        int s[8];
        float msk[8];
#pragma unroll
        for (int j = 0; j < 8; ++j) {
            bool ok = (t + j) < cnt;
            s[j] = ok ? ((j < 4) ? sv0[j] : sv1[j - 4]) : 0;
            msk[j] = ok ? 1.f : 0.f;
        }
        uint2 u[8];
#pragma unroll
        for (int j = 0; j < 8; ++j)
            u[j] = *(const uint2*)(fp + (size_t)s[j] * 64 + sub * 4);
        float w[8];
#pragma unroll
        for (int j = 0; j < 8; ++j) {
            float xx = fminf(leakyf(el[s[j]] + ern), 80.f);
            w[j] = msk[j] * __expf(xx);
        }
#pragma unroll
        for (int j = 0; j < 8; ++j) {
            den += w[j];
            acc[0] += w[j] * bflo(u[j].x);
            acc[1] += w[j] * bfhi(u[j].x);
            acc[2] += w[j] * bflo(u[j].y);
            acc[3] += w[j] * bfhi(u[j].y);
        }
    }

    if (node >= n) return;

    float inv = den > 0.f ? 1.f / den : 0.f;
    float4 rv = *(const float4*)(resf + (size_t)node * 64 + sub * 4);
    float v[4];
    v[0] = acc[0] * inv + rv.x;
    v[1] = acc[1] * inv + rv.y;
    v[2] = acc[2] * inv + rv.z;
    v[3] = acc[3] * inv + rv.w;

#pragma unroll
    for (int i = 0; i < 4; ++i) {
        int p = sub * 4 + i;                 // permuted slot
        int c = (p & 3) * 16 + (p >> 2);     // true column
        outv[(size_t)node * 64 + c] = v[i];
    }
}

// ---------------- launcher ----------------------------------------------------------------
extern "C" void kernel_launch(void* const* d_in, const int* in_sizes, int n_in,
                              void* d_out, int out_size, void* d_ws, size_t ws_size,
                              hipStream_t stream) {
    const float* x      = (const float*)d_in[0];
    const float* W1     = (const float*)d_in[1];
    const float* al1    = (const float*)d_in[2];
    const float* ar1    = (const float*)d_in[3];
    const float* W2     = (const float*)d_in[4];
    const float* al2    = (const float*)d_in[5];
    const float* ar2    = (const float*)d_in[6];
    const float* W3     = (const float*)d_in[7];
    const float* al3    = (const float*)d_in[8];
    const float* ar3    = (const float*)d_in[9];
    const float* res_W3 = (const float*)d_in[10];
    const int*   src    = (const int*)d_in[11];
    const int*   dst    = (const int*)d_in[12];

    const int N = in_sizes[0] / 128;    // 50000
    const int E = in_sizes[11];         // 500000

    float* out = (float*)d_out;

    // workspace layout (16B alignment maintained)
    unsigned short* featb = (unsigned short*)d_ws;          // [N,256] (layer3: [N,64])
    unsigned short* h1    = featb + (size_t)N * 256;        // [N,256]
    unsigned short* h2    = h1 + (size_t)N * 256;           // [N,256]
    unsigned short* W1t   = h2 + (size_t)N * 256;           // [256,128]
    unsigned short* W2t   = W1t + 256 * 128;                // [256,256]
    unsigned short* W3c   = W2t + 256 * 256;                // [128,256] = [W3t | RW3t]
    float* resf = (float*)(W3c + 128 * 256);                // [N,64]
    float* el   = resf + (size_t)N * 64;                    // [N,4]
    float* er   = el + (size_t)N * 4;                       // [N,4]
    int* offsets = (int*)(er + (size_t)N * 4);              // [N+1] (padded)
    int* cursor  = offsets + (N + 8);                       // [N]
    int* csr_src = cursor + N;                              // [E] + 256 pad
    int* bsums   = csr_src + E + 256;                       // [64]

    const int T = 256;
    const int scan_blocks = (N + 1023) / 1024;  // 49 (<= 64 for add_off)
    const int edge_blocks = (E + T - 1) / T;
    const int zero_blocks = (N + 255) / 256;

    // ---- prep: weight conversion + zero hist counts (one dispatch) ----
    prep<<<512 + zero_blocks, T, 0, stream>>>(W1, W2, W3, res_W3, W1t, W2t, W3c, cursor, N);

    // ---- CSR by dst ----
    hist_kernel<<<edge_blocks, T, 0, stream>>>(dst, cursor, E);
    scan_block<<<scan_blocks, 1024, 0, stream>>>(cursor, offsets, bsums, N);
    add_off<<<scan_blocks, 1024, 0, stream>>>(bsums, offsets, cursor, N, E, scan_blocks);
    scatter_kernel<<<edge_blocks, T, 0, stream>>>(src, dst, cursor, csr_src, E);

    int gemm12_blocks = (N + 63) / 64;
    int gemm3_blocks = (N + 127) / 128;
    int agg4_blocks = (N + 7) / 8;
    int agg1_blocks = (N + 15) / 16;

    // ---- Layer 1 ----
    gemm_l12<true><<<gemm12_blocks, T, 0, stream>>>(x, W1t, featb, al1, ar1, el, er, N, 128);
    gat_agg4<0, 1><<<agg4_blocks, T, 0, stream>>>(featb, el, er, offsets, csr_src, nullptr, h1, N);

    // ---- Layer 2 ----
    gemm_l12<false><<<gemm12_blocks, T, 0, stream>>>(h1, W2t, featb, al2, ar2, el, er, N, 256);
    gat_agg4<1, 1><<<agg4_blocks, T, 0, stream>>>(featb, el, er, offsets, csr_src, h1, h2, N);

    // ---- Layer 3 ----
    gemm_l3<<<gemm3_blocks, T, 0, stream>>>(h2, W3c, featb, resf, al3, ar3, el, er, N);
    gat_agg1<<<agg1_blocks, T, 0, stream>>>(featb, el, er, offsets, csr_src, resf, out, N);
}

// Round 10
// 273.853 us; speedup vs baseline: 1.0674x; 1.0674x over previous
//
#include <hip/hip_runtime.h>
#include <hip/hip_bf16.h>
#include <math.h>

#define SLOPE 0.2f

typedef __attribute__((ext_vector_type(8))) short short8;
typedef __attribute__((ext_vector_type(4))) float f32x4;
typedef __attribute__((ext_vector_type(4))) int   i32x4;

static __device__ __forceinline__ float leakyf(float x) { return x >= 0.f ? x : SLOPE * x; }
static __device__ __forceinline__ float bflo(unsigned u) { return __builtin_bit_cast(float, u << 16); }
static __device__ __forceinline__ float bfhi(unsigned u) { return __builtin_bit_cast(float, u & 0xffff0000u); }
static __device__ __forceinline__ unsigned short f2bf(float f) {
    unsigned u = __builtin_bit_cast(unsigned, f);
    return (unsigned short)((u + 0x7fff + ((u >> 16) & 1)) >> 16);  // RNE
}

struct __align__(8) us4 { unsigned short a, b, c, d; };

// Permuted within-head column layout: slot p (in [0,64) of a head block) holds true
// column c64(p) = (p&3)*16 + (p>>2).  Inverse: p(c) = (c&15)*4 + (c>>4).

// ---------------- prep: weight transpose/convert/K-permute + zero counts + zero flags ----
__global__ __launch_bounds__(256) void prep(const float* __restrict__ W1,
                                            const float* __restrict__ W2,
                                            const float* __restrict__ W3,
                                            const float* __restrict__ rW3,
                                            unsigned short* __restrict__ W1t,
                                            unsigned short* __restrict__ W2t,
                                            unsigned short* __restrict__ W3c,
                                            int* __restrict__ counts,
                                            int* __restrict__ bflag, int n) {
    int b = blockIdx.x;
    if (b < 512) {
        int i = b * 256 + threadIdx.x;
        const float* W; unsigned short* Wt; int K, lNc, idx; bool permK;
        if (i < 32768)       { W = W1;  Wt = W1t;            K = 128; lNc = 8; idx = i;          permK = false; }
        else if (i < 98304)  { W = W2;  Wt = W2t;            K = 256; lNc = 8; idx = i - 32768;  permK = true; }
        else if (i < 114688) { W = W3;  Wt = W3c;            K = 256; lNc = 6; idx = i - 98304;  permK = true; }
        else                 { W = rW3; Wt = W3c + 64 * 256; K = 256; lNc = 6; idx = i - 114688; permK = true; }
        int k = idx >> lNc, nn = idx & ((1 << lNc) - 1);
        int kp = permK ? ((k & ~63) | (((k & 15) << 2) | ((k & 63) >> 4))) : k;
        Wt[nn * K + kp] = f2bf(W[idx]);
    } else {
        if (b == 512 && threadIdx.x < 64) bflag[threadIdx.x] = 0;  // reset lookback flags (graph replay!)
        int idx = (b - 512) * 256 + threadIdx.x;
        if (idx < n) counts[idx] = 0;
    }
}

// ---------------- MFMA GEMM body (layers 1/2) + fused attention projections --------------
template<bool A_F32>
static __device__ __forceinline__ void gemm_l12_body(int bid, const void* __restrict__ Av,
                                                     const unsigned short* __restrict__ Wt,
                                                     unsigned short* __restrict__ outb,
                                                     const float* __restrict__ al,
                                                     const float* __restrict__ ar,
                                                     float* __restrict__ el,
                                                     float* __restrict__ er,
                                                     int M, int K) {
    const int lane = threadIdx.x & 63;
    const int wid = threadIdx.x >> 6;       // head
    const int rlo = lane & 15;
    const int q = lane >> 4;
    const int kg = q * 8;
    const int m0 = bid * 64;
    const int cbase = wid * 64;

    f32x4 acc[4][4];
#pragma unroll
    for (int mf = 0; mf < 4; ++mf)
#pragma unroll
        for (int nf = 0; nf < 4; ++nf) acc[mf][nf] = (f32x4){0.f, 0.f, 0.f, 0.f};

    for (int k0 = 0; k0 < K; k0 += 32) {
        short8 a[4];
#pragma unroll
        for (int mf = 0; mf < 4; ++mf) {
            int r = m0 + mf * 16 + rlo;
            if (r >= M) r = M - 1;  // clamp; affects only unstored rows
            if (A_F32) {
                const float* ap = (const float*)Av + (size_t)r * K + k0 + kg;
                float4 f0 = *(const float4*)ap;
                float4 f1 = *(const float4*)(ap + 4);
                short8 t;
                t[0] = f2bf(f0.x); t[1] = f2bf(f0.y); t[2] = f2bf(f0.z); t[3] = f2bf(f0.w);
                t[4] = f2bf(f1.x); t[5] = f2bf(f1.y); t[6] = f2bf(f1.z); t[7] = f2bf(f1.w);
                a[mf] = t;
            } else {
                a[mf] = *(const short8*)((const unsigned short*)Av + (size_t)r * K + k0 + kg);
            }
        }
#pragma unroll
        for (int nf = 0; nf < 4; ++nf) {
            short8 b = *(const short8*)(Wt + (size_t)(cbase + nf * 16 + rlo) * K + k0 + kg);
#pragma unroll
            for (int mf = 0; mf < 4; ++mf)
                acc[mf][nf] = __builtin_amdgcn_mfma_f32_16x16x32_bf16(a[mf], b, acc[mf][nf], 0, 0, 0);
        }
    }

    float alv[4], arv[4];
#pragma unroll
    for (int nf = 0; nf < 4; ++nf) {
        alv[nf] = al[cbase + nf * 16 + rlo];
        arv[nf] = ar[cbase + nf * 16 + rlo];
    }

#pragma unroll
    for (int mf = 0; mf < 4; ++mf) {
#pragma unroll
        for (int reg = 0; reg < 4; ++reg) {
            int r = m0 + mf * 16 + q * 4 + reg;
            float pl = 0.f, pr = 0.f;
#pragma unroll
            for (int nf = 0; nf < 4; ++nf) {
                pl += acc[mf][nf][reg] * alv[nf];
                pr += acc[mf][nf][reg] * arv[nf];
            }
#pragma unroll
            for (int off = 1; off < 16; off <<= 1) {
                pl += __shfl_xor(pl, off);
                pr += __shfl_xor(pr, off);
            }
            if (rlo == 0 && r < M) {
                el[(size_t)r * 4 + wid] = pl;
                er[(size_t)r * 4 + wid] = pr;
            }
            if (r < M) {
                us4 o = {f2bf(acc[mf][0][reg]), f2bf(acc[mf][1][reg]),
                         f2bf(acc[mf][2][reg]), f2bf(acc[mf][3][reg])};
                *(us4*)(outb + (size_t)r * 256 + cbase + rlo * 4) = o;  // permuted slots
            }
        }
    }
}

template<bool A_F32>
__global__ __launch_bounds__(256) void gemm_l12(const void* __restrict__ Av,
                                                const unsigned short* __restrict__ Wt,
                                                unsigned short* __restrict__ outb,
                                                const float* __restrict__ al,
                                                const float* __restrict__ ar,
                                                float* __restrict__ el,
                                                float* __restrict__ er, int M, int K) {
    gemm_l12_body<A_F32>(blockIdx.x, Av, Wt, outb, al, ar, el, er, M, K);
}

// ---------------- fused layer-1 GEMM + CSR scatter (independent block ranges) ------------
__global__ __launch_bounds__(256) void gemm1_scatter(const float* __restrict__ x,
                                                     const unsigned short* __restrict__ W1t,
                                                     unsigned short* __restrict__ featb,
                                                     const float* __restrict__ al,
                                                     const float* __restrict__ ar,
                                                     float* __restrict__ el,
                                                     float* __restrict__ er,
                                                     int M, int K, int gemm_blocks,
                                                     const int* __restrict__ src,
                                                     const int* __restrict__ dst,
                                                     int* __restrict__ cursor,
                                                     int* __restrict__ csr_src,
                                                     int* __restrict__ csr_dst, int E) {
    int b = blockIdx.x;
    if (b < gemm_blocks) {
        gemm_l12_body<true>(b, x, W1t, featb, al, ar, el, er, M, K);
    } else {
        int i = (b - gemm_blocks) * 256 + threadIdx.x;
        if (i < E) {
            int d = dst[i];
            int pos = atomicAdd(&cursor[d], 1);
            csr_src[pos] = src[i];
            csr_dst[pos] = d;
        }
    }
}

// ---------------- layer-3 fused GEMM: h2(perm) @ [W3 | res_W3] ---------------------------
__global__ __launch_bounds__(256) void gemm_l3(const unsigned short* __restrict__ A,
                                               const unsigned short* __restrict__ Wt,
                                               unsigned short* __restrict__ featb,
                                               float* __restrict__ resf,
                                               const float* __restrict__ al,
                                               const float* __restrict__ ar,
                                               float* __restrict__ el,
                                               float* __restrict__ er, int M) {
    const int K = 256;
    const int lane = threadIdx.x & 63;
    const int wid = threadIdx.x >> 6;
    const int rlo = lane & 15;
    const int q = lane >> 4;
    const int kg = q * 8;
    const int m0 = blockIdx.x * 128 + (wid >> 1) * 64;
    const int ch = wid & 1;
    const int cbase = ch * 64;

    f32x4 acc[4][4];
#pragma unroll
    for (int mf = 0; mf < 4; ++mf)
#pragma unroll
        for (int nf = 0; nf < 4; ++nf) acc[mf][nf] = (f32x4){0.f, 0.f, 0.f, 0.f};

    for (int k0 = 0; k0 < K; k0 += 32) {
        short8 a[4];
#pragma unroll
        for (int mf = 0; mf < 4; ++mf) {
            int r = m0 + mf * 16 + rlo;
            if (r >= M) r = M - 1;
            a[mf] = *(const short8*)(A + (size_t)r * K + k0 + kg);
        }
#pragma unroll
        for (int nf = 0; nf < 4; ++nf) {
            short8 b = *(const short8*)(Wt + (size_t)(cbase + nf * 16 + rlo) * K + k0 + kg);
#pragma unroll
            for (int mf = 0; mf < 4; ++mf)
                acc[mf][nf] = __builtin_amdgcn_mfma_f32_16x16x32_bf16(a[mf], b, acc[mf][nf], 0, 0, 0);
        }
    }

    float alv[4], arv[4];
    if (ch == 0) {
#pragma unroll
        for (int nf = 0; nf < 4; ++nf) {
            alv[nf] = al[nf * 16 + rlo];
            arv[nf] = ar[nf * 16 + rlo];
        }
    }

#pragma unroll
    for (int mf = 0; mf < 4; ++mf) {
#pragma unroll
        for (int reg = 0; reg < 4; ++reg) {
            int r = m0 + mf * 16 + q * 4 + reg;
            if (ch == 0) {
                float pl = 0.f, pr = 0.f;
#pragma unroll
                for (int nf = 0; nf < 4; ++nf) {
                    pl += acc[mf][nf][reg] * alv[nf];
                    pr += acc[mf][nf][reg] * arv[nf];
                }
#pragma unroll
                for (int off = 1; off < 16; off <<= 1) {
                    pl += __shfl_xor(pl, off);
                    pr += __shfl_xor(pr, off);
                }
                if (rlo == 0 && r < M) { el[r] = pl; er[r] = pr; }
                if (r < M) {
                    us4 o = {f2bf(acc[mf][0][reg]), f2bf(acc[mf][1][reg]),
                             f2bf(acc[mf][2][reg]), f2bf(acc[mf][3][reg])};
                    *(us4*)(featb + (size_t)r * 64 + rlo * 4) = o;  // permuted
                }
            } else if (r < M) {
                float4 o = {acc[mf][0][reg], acc[mf][1][reg], acc[mf][2][reg], acc[mf][3][reg]};
                *(float4*)(resf + (size_t)r * 64 + rlo * 4) = o;    // permuted
            }
        }
    }
}

// ---------------- CSR build --------------------------------------------------------------
__global__ void hist_kernel(const int* __restrict__ dst, int* __restrict__ counts, int e) {
    int i = blockIdx.x * blockDim.x + threadIdx.x;
    if (i < e) atomicAdd(&counts[dst[i]], 1);
}

// single-dispatch exclusive scan with decoupled lookback (49 blocks <= 256 CUs, co-resident)
__global__ __launch_bounds__(1024) void scan_lookback(const int* __restrict__ counts,
                                                      int* __restrict__ offsets,
                                                      int* __restrict__ cursor,
                                                      int* __restrict__ bsum,
                                                      int* __restrict__ bflag, int n, int e) {
    __shared__ int ws[16];
    __shared__ int base_s;
    int tid = threadIdx.x, lane = tid & 63, wid = tid >> 6, bid = blockIdx.x;
    int idx = bid * 1024 + tid;
    int v = (idx < n) ? counts[idx] : 0;
    int s = v;
#pragma unroll
    for (int off = 1; off < 64; off <<= 1) {
        int t = __shfl_up(s, off);
        if (lane >= off) s += t;
    }
    if (lane == 63) ws[wid] = s;
    __syncthreads();
    if (tid < 16) {
        int w2 = ws[tid];
#pragma unroll
        for (int off = 1; off < 16; off <<= 1) {
            int t = __shfl_up(w2, off);
            if (tid >= off) w2 += t;
        }
        ws[tid] = w2;
    }
    __syncthreads();
    int local_ex = (wid ? ws[wid - 1] : 0) + s - v;
    if (tid == 0) {
        __hip_atomic_store(&bsum[bid], ws[15], __ATOMIC_RELAXED, __HIP_MEMORY_SCOPE_AGENT);
        __hip_atomic_store(&bflag[bid], 1, __ATOMIC_RELEASE, __HIP_MEMORY_SCOPE_AGENT);
    }
    if (wid == 0) {
        int acc = 0;
        for (int p = lane; p < bid; p += 64) {
            while (__hip_atomic_load(&bflag[p], __ATOMIC_ACQUIRE, __HIP_MEMORY_SCOPE_AGENT) == 0) {}
            acc += __hip_atomic_load(&bsum[p], __ATOMIC_RELAXED, __HIP_MEMORY_SCOPE_AGENT);
        }
#pragma unroll
        for (int off = 32; off > 0; off >>= 1) acc += __shfl_xor(acc, off);
        if (lane == 0) base_s = acc;
    }
    __syncthreads();
    int val = base_s + local_ex;
    if (idx < n) {
        offsets[idx] = val;
        cursor[idx] = val;
    }
    if (idx == 0) offsets[n] = e;
}

// ---------------- edge-parallel score precompute (head-major w) --------------------------
template<int H>
__global__ __launch_bounds__(256) void edge_scores(const int* __restrict__ csr_src,
                                                   const int* __restrict__ csr_dst,
                                                   const float* __restrict__ el,
                                                   const float* __restrict__ er,
                                                   float* __restrict__ w, int E) {
    int e4 = (blockIdx.x * 256 + threadIdx.x) * 4;
    if (e4 >= E) return;
    i32x4 s = *(const i32x4*)(csr_src + e4);
    i32x4 d = *(const i32x4*)(csr_dst + e4);
    if (H == 4) {
        float4 o0, o1, o2, o3;
        float* op[4] = {&o0.x, &o1.x, &o2.x, &o3.x};
#pragma unroll
        for (int j = 0; j < 4; ++j) {
            float4 l = *(const float4*)(el + (size_t)s[j] * 4);
            float4 r = *(const float4*)(er + (size_t)d[j] * 4);
            op[0][j] = __expf(fminf(leakyf(l.x + r.x), 80.f));
            op[1][j] = __expf(fminf(leakyf(l.y + r.y), 80.f));
            op[2][j] = __expf(fminf(leakyf(l.z + r.z), 80.f));
            op[3][j] = __expf(fminf(leakyf(l.w + r.w), 80.f));
        }
        *(float4*)(w + 0 * (size_t)E + e4) = o0;
        *(float4*)(w + 1 * (size_t)E + e4) = o1;
        *(float4*)(w + 2 * (size_t)E + e4) = o2;
        *(float4*)(w + 3 * (size_t)E + e4) = o3;
    } else {
        float4 o;
#pragma unroll
        for (int j = 0; j < 4; ++j)
            (&o.x)[j] = __expf(fminf(leakyf(el[s[j]] + er[d[j]]), 80.f));
        *(float4*)(w + e4) = o;
    }
}

// ---------------- H=4 aggregate: 2 nodes per wave, 16B/lane gathers ----------------------
template<int RES, int ACT>
__global__ __launch_bounds__(256) void gat_agg4(const unsigned short* __restrict__ fp,
                                                const float* __restrict__ wbuf,
                                                const int* __restrict__ offsets,
                                                const int* __restrict__ csr_src,
                                                const unsigned short* __restrict__ resid,
                                                unsigned short* __restrict__ outb,
                                                int n, int E) {
    int wv = threadIdx.x >> 6;
    int lane = threadIdx.x & 63;
    int half = lane >> 5;
    int sub = lane & 31;
    int node = blockIdx.x * 8 + wv * 2 + half;

    int e0 = 0, e1 = 0;
    if (node < n) { e0 = offsets[node]; e1 = offsets[node + 1]; }
    int cnt = e1 - e0;
    int ocnt = __shfl_xor(cnt, 32);
    int mc = cnt > ocnt ? cnt : ocnt;

    const float* wb = wbuf + (size_t)(sub >> 3) * E;

    float den = 0.f;
    float acc[8] = {0.f, 0.f, 0.f, 0.f, 0.f, 0.f, 0.f, 0.f};

    for (int t = 0; t < mc; t += 8) {
        i32x4 sv0, sv1;
        f32x4 wv0, wv1;
        __builtin_memcpy(&sv0, csr_src + e0 + t, 16);      // overreads stay inside d_ws pad
        __builtin_memcpy(&sv1, csr_src + e0 + t + 4, 16);
        __builtin_memcpy(&wv0, wb + e0 + t, 16);
        __builtin_memcpy(&wv1, wb + e0 + t + 4, 16);
        int s[8];
        float w[8];
#pragma unroll
        for (int j = 0; j < 8; ++j) {
            bool ok = (t + j) < cnt;
            int sj = (j < 4) ? sv0[j] : sv1[j - 4];
            float wj = (j < 4) ? wv0[j] : wv1[j - 4];
            s[j] = ok ? sj : 0;
            w[j] = ok ? wj : 0.f;
        }
        uint4 u[8];
#pragma unroll
        for (int j = 0; j < 8; ++j)
            u[j] = *(const uint4*)(fp + (size_t)s[j] * 256 + sub * 8);
#pragma unroll
        for (int j = 0; j < 8; ++j) {
            den += w[j];
            acc[0] += w[j] * bflo(u[j].x);
            acc[1] += w[j] * bfhi(u[j].x);
            acc[2] += w[j] * bflo(u[j].y);
            acc[3] += w[j] * bfhi(u[j].y);
            acc[4] += w[j] * bflo(u[j].z);
            acc[5] += w[j] * bfhi(u[j].z);
            acc[6] += w[j] * bflo(u[j].w);
            acc[7] += w[j] * bfhi(u[j].w);
        }
    }

    if (node >= n) return;

    float inv = den > 0.f ? 1.f / den : 0.f;
    float v[8];
#pragma unroll
    for (int i = 0; i < 8; ++i) v[i] = acc[i] * inv;

    if (RES == 1) {
        uint4 ru = *(const uint4*)(resid + (size_t)node * 256 + sub * 8);
        v[0] += bflo(ru.x); v[1] += bfhi(ru.x);
        v[2] += bflo(ru.y); v[3] += bfhi(ru.y);
        v[4] += bflo(ru.z); v[5] += bfhi(ru.z);
        v[6] += bflo(ru.w); v[7] += bfhi(ru.w);
    }
    if (ACT == 1) {
#pragma unroll
        for (int i = 0; i < 8; ++i) v[i] = v[i] > 0.f ? v[i] : __expf(v[i]) - 1.f;
    }
    uint4 o;
    o.x = (unsigned)f2bf(v[0]) | ((unsigned)f2bf(v[1]) << 16);
    o.y = (unsigned)f2bf(v[2]) | ((unsigned)f2bf(v[3]) << 16);
    o.z = (unsigned)f2bf(v[4]) | ((unsigned)f2bf(v[5]) << 16);
    o.w = (unsigned)f2bf(v[6]) | ((unsigned)f2bf(v[7]) << 16);
    *(uint4*)(outb + (size_t)node * 256 + sub * 8) = o;
}

// ---------------- H=1 aggregate: 4 nodes per wave, 8B/lane gathers -----------------------
__global__ __launch_bounds__(256) void gat_agg1(const unsigned short* __restrict__ fp,
                                                const float* __restrict__ wbuf,
                                                const int* __restrict__ offsets,
                                                const int* __restrict__ csr_src,
                                                const float* __restrict__ resf,
                                                float* __restrict__ outv, int n, int E) {
    int wv = threadIdx.x >> 6;
    int lane = threadIdx.x & 63;
    int sub = lane & 15;
    int node = blockIdx.x * 16 + wv * 4 + (lane >> 4);

    int e0 = 0, e1 = 0;
    if (node < n) { e0 = offsets[node]; e1 = offsets[node + 1]; }
    int cnt = e1 - e0;
    int m1 = __shfl_xor(cnt, 16);
    int mc = cnt > m1 ? cnt : m1;
    int m2 = __shfl_xor(mc, 32);
    mc = mc > m2 ? mc : m2;

    float den = 0.f;
    float acc[4] = {0.f, 0.f, 0.f, 0.f};

    for (int t = 0; t < mc; t += 8) {
        i32x4 sv0, sv1;
        f32x4 wv0, wv1;
        __builtin_memcpy(&sv0, csr_src + e0 + t, 16);
        __builtin_memcpy(&sv1, csr_src + e0 + t + 4, 16);
        __builtin_memcpy(&wv0, wbuf + e0 + t, 16);
        __builtin_memcpy(&wv1, wbuf + e0 + t + 4, 16);
        int s[8];
        float w[8];
#pragma unroll
        for (int j = 0; j < 8; ++j) {
            bool ok = (t + j) < cnt;
            int sj = (j < 4) ? sv0[j] : sv1[j - 4];
            float wj = (j < 4) ? wv0[j] : wv1[j - 4];
            s[j] = ok ? sj : 0;
            w[j] = ok ? wj : 0.f;
        }
        uint2 u[8];
#pragma unroll
        for (int j = 0; j < 8; ++j)
            u[j] = *(const uint2*)(fp + (size_t)s[j] * 64 + sub * 4);
#pragma unroll
        for (int j = 0; j < 8; ++j) {
            den += w[j];
            acc[0] += w[j] * bflo(u[j].x);
            acc[1] += w[j] * bfhi(u[j].x);
            acc[2] += w[j] * bflo(u[j].y);
            acc[3] += w[j] * bfhi(u[j].y);
        }
    }

    if (node >= n) return;

    float inv = den > 0.f ? 1.f / den : 0.f;
    float4 rv = *(const float4*)(resf + (size_t)node * 64 + sub * 4);
    float v[4];
    v[0] = acc[0] * inv + rv.x;
    v[1] = acc[1] * inv + rv.y;
    v[2] = acc[2] * inv + rv.z;
    v[3] = acc[3] * inv + rv.w;

#pragma unroll
    for (int i = 0; i < 4; ++i) {
        int p = sub * 4 + i;                 // permuted slot
        int c = (p & 3) * 16 + (p >> 2);     // true column
        outv[(size_t)node * 64 + c] = v[i];
    }
}

// ---------------- launcher ----------------------------------------------------------------
extern "C" void kernel_launch(void* const* d_in, const int* in_sizes, int n_in,
                              void* d_out, int out_size, void* d_ws, size_t ws_size,
                              hipStream_t stream) {
    const float* x      = (const float*)d_in[0];
    const float* W1     = (const float*)d_in[1];
    const float* al1    = (const float*)d_in[2];
    const float* ar1    = (const float*)d_in[3];
    const float* W2     = (const float*)d_in[4];
    const float* al2    = (const float*)d_in[5];
    const float* ar2    = (const float*)d_in[6];
    const float* W3     = (const float*)d_in[7];
    const float* al3    = (const float*)d_in[8];
    const float* ar3    = (const float*)d_in[9];
    const float* res_W3 = (const float*)d_in[10];
    const int*   src    = (const int*)d_in[11];
    const int*   dst    = (const int*)d_in[12];

    const int N = in_sizes[0] / 128;    // 50000
    const int E = in_sizes[11];         // 500000

    float* out = (float*)d_out;

    // workspace layout (16B alignment maintained)
    unsigned short* featb = (unsigned short*)d_ws;          // [N,256] (layer3: [N,64])
    unsigned short* h1    = featb + (size_t)N * 256;        // [N,256]
    unsigned short* h2    = h1 + (size_t)N * 256;           // [N,256]
    unsigned short* W1t   = h2 + (size_t)N * 256;           // [256,128]
    unsigned short* W2t   = W1t + 256 * 128;                // [256,256]
    unsigned short* W3c   = W2t + 256 * 256;                // [128,256] = [W3t | RW3t]
    float* resf = (float*)(W3c + 128 * 256);                // [N,64]
    float* el   = resf + (size_t)N * 64;                    // [N,4]
    float* er   = el + (size_t)N * 4;                       // [N,4]
    float* wbuf = er + (size_t)N * 4;                       // [4][E] head-major
    int* offsets = (int*)(wbuf + (size_t)E * 4);            // [N+1] (padded)
    int* cursor  = offsets + (N + 8);                       // [N]
    int* csr_src = cursor + N;                              // [E] + pad
    int* csr_dst = csr_src + E + 64;                        // [E]
    int* bsums   = csr_dst + E;                             // [64]
    int* bflag   = bsums + 64;                              // [64]

    const int T = 256;
    const int scan_blocks = (N + 1023) / 1024;              // 49 (co-resident on 256 CUs)
    const int edge_blocks = (E + T - 1) / T;                // 1954
    const int zero_blocks = (N + 255) / 256;                // 196
    const int es_blocks = (E / 4 + T - 1) / T;              // 489

    int gemm12_blocks = (N + 63) / 64;                      // 782
    int gemm3_blocks = (N + 127) / 128;                     // 391
    int agg4_blocks = (N + 7) / 8;                          // 6250
    int agg1_blocks = (N + 15) / 16;                        // 3125

    // ---- 1: prep (weights + zero counts + zero flags) ----
    prep<<<512 + zero_blocks, T, 0, stream>>>(W1, W2, W3, res_W3, W1t, W2t, W3c, cursor, bflag, N);
    // ---- 2: histogram ----
    hist_kernel<<<edge_blocks, T, 0, stream>>>(dst, cursor, E);
    // ---- 3: single-dispatch scan (offsets + cursor) ----
    scan_lookback<<<scan_blocks, 1024, 0, stream>>>(cursor, offsets, cursor, bsums, bflag, N, E);
    // ---- 4: layer-1 GEMM (+el/er) fused with CSR scatter ----
    gemm1_scatter<<<gemm12_blocks + edge_blocks, T, 0, stream>>>(x, W1t, featb, al1, ar1, el, er,
                                                                 N, 128, gemm12_blocks,
                                                                 src, dst, cursor, csr_src, csr_dst, E);
    // ---- 5-6: layer-1 scores + aggregate ----
    edge_scores<4><<<es_blocks, T, 0, stream>>>(csr_src, csr_dst, el, er, wbuf, E);
    gat_agg4<0, 1><<<agg4_blocks, T, 0, stream>>>(featb, wbuf, offsets, csr_src, nullptr, h1, N, E);
    // ---- 7-9: layer 2 ----
    gemm_l12<false><<<gemm12_blocks, T, 0, stream>>>(h1, W2t, featb, al2, ar2, el, er, N, 256);
    edge_scores<4><<<es_blocks, T, 0, stream>>>(csr_src, csr_dst, el, er, wbuf, E);
    gat_agg4<1, 1><<<agg4_blocks, T, 0, stream>>>(featb, wbuf, offsets, csr_src, h1, h2, N, E);
    // ---- 10-12: layer 3 ----
    gemm_l3<<<gemm3_blocks, T, 0, stream>>>(h2, W3c, featb, resf, al3, ar3, el, er, N);
    edge_scores<1><<<es_blocks, T, 0, stream>>>(csr_src, csr_dst, el, er, wbuf, E);
    gat_agg1<<<agg1_blocks, T, 0, stream>>>(featb, wbuf, offsets, csr_src, resf, out, N, E);
}

// Round 11
// 263.519 us; speedup vs baseline: 1.1092x; 1.0392x over previous
//
#include <hip/hip_runtime.h>
#include <hip/hip_bf16.h>
#include <math.h>

#define SLOPE 0.2f

typedef __attribute__((ext_vector_type(8))) short short8;
typedef __attribute__((ext_vector_type(4))) float f32x4;
typedef __attribute__((ext_vector_type(4))) int   i32x4;

static __device__ __forceinline__ float leakyf(float x) { return x >= 0.f ? x : SLOPE * x; }
static __device__ __forceinline__ float bflo(unsigned u) { return __builtin_bit_cast(float, u << 16); }
static __device__ __forceinline__ float bfhi(unsigned u) { return __builtin_bit_cast(float, u & 0xffff0000u); }
static __device__ __forceinline__ unsigned short f2bf(float f) {
    unsigned u = __builtin_bit_cast(unsigned, f);
    return (unsigned short)((u + 0x7fff + ((u >> 16) & 1)) >> 16);  // RNE
}

struct __align__(8) us4 { unsigned short a, b, c, d; };

// Permuted within-head column layout: slot p (in [0,64) of a head block) holds true
// column c64(p) = (p&3)*16 + (p>>2).  Inverse: p(c) = (c&15)*4 + (c>>4).

// ---------------- prep: weight transpose/convert/K-permute + zero counts + zero flags ----
__global__ __launch_bounds__(256) void prep(const float* __restrict__ W1,
                                            const float* __restrict__ W2,
                                            const float* __restrict__ W3,
                                            const float* __restrict__ rW3,
                                            unsigned short* __restrict__ W1t,
                                            unsigned short* __restrict__ W2t,
                                            unsigned short* __restrict__ W3c,
                                            int* __restrict__ counts,
                                            int* __restrict__ bflag, int n) {
    int b = blockIdx.x;
    if (b < 512) {
        int i = b * 256 + threadIdx.x;
        const float* W; unsigned short* Wt; int K, lNc, idx; bool permK;
        if (i < 32768)       { W = W1;  Wt = W1t;            K = 128; lNc = 8; idx = i;          permK = false; }
        else if (i < 98304)  { W = W2;  Wt = W2t;            K = 256; lNc = 8; idx = i - 32768;  permK = true; }
        else if (i < 114688) { W = W3;  Wt = W3c;            K = 256; lNc = 6; idx = i - 98304;  permK = true; }
        else                 { W = rW3; Wt = W3c + 64 * 256; K = 256; lNc = 6; idx = i - 114688; permK = true; }
        int k = idx >> lNc, nn = idx & ((1 << lNc) - 1);
        int kp = permK ? ((k & ~63) | (((k & 15) << 2) | ((k & 63) >> 4))) : k;
        Wt[nn * K + kp] = f2bf(W[idx]);
    } else {
        if (b == 512 && threadIdx.x < 64) bflag[threadIdx.x] = 0;  // reset lookback flags (graph replay!)
        int idx = (b - 512) * 256 + threadIdx.x;
        if (idx < n) counts[idx] = 0;
    }
}

// ---------------- MFMA GEMM body (layers 1/2) + fused attention projections --------------
template<bool A_F32>
static __device__ __forceinline__ void gemm_l12_body(int bid, const void* __restrict__ Av,
                                                     const unsigned short* __restrict__ Wt,
                                                     unsigned short* __restrict__ outb,
                                                     const float* __restrict__ al,
                                                     const float* __restrict__ ar,
                                                     float* __restrict__ el,
                                                     float* __restrict__ er,
                                                     int M, int K) {
    const int lane = threadIdx.x & 63;
    const int wid = threadIdx.x >> 6;       // head
    const int rlo = lane & 15;
    const int q = lane >> 4;
    const int kg = q * 8;
    const int m0 = bid * 64;
    const int cbase = wid * 64;

    f32x4 acc[4][4];
#pragma unroll
    for (int mf = 0; mf < 4; ++mf)
#pragma unroll
        for (int nf = 0; nf < 4; ++nf) acc[mf][nf] = (f32x4){0.f, 0.f, 0.f, 0.f};

    for (int k0 = 0; k0 < K; k0 += 32) {
        short8 a[4];
#pragma unroll
        for (int mf = 0; mf < 4; ++mf) {
            int r = m0 + mf * 16 + rlo;
            if (r >= M) r = M - 1;  // clamp; affects only unstored rows
            if (A_F32) {
                const float* ap = (const float*)Av + (size_t)r * K + k0 + kg;
                float4 f0 = *(const float4*)ap;
                float4 f1 = *(const float4*)(ap + 4);
                short8 t;
                t[0] = f2bf(f0.x); t[1] = f2bf(f0.y); t[2] = f2bf(f0.z); t[3] = f2bf(f0.w);
                t[4] = f2bf(f1.x); t[5] = f2bf(f1.y); t[6] = f2bf(f1.z); t[7] = f2bf(f1.w);
                a[mf] = t;
            } else {
                a[mf] = *(const short8*)((const unsigned short*)Av + (size_t)r * K + k0 + kg);
            }
        }
#pragma unroll
        for (int nf = 0; nf < 4; ++nf) {
            short8 b = *(const short8*)(Wt + (size_t)(cbase + nf * 16 + rlo) * K + k0 + kg);
#pragma unroll
            for (int mf = 0; mf < 4; ++mf)
                acc[mf][nf] = __builtin_amdgcn_mfma_f32_16x16x32_bf16(a[mf], b, acc[mf][nf], 0, 0, 0);
        }
    }

    float alv[4], arv[4];
#pragma unroll
    for (int nf = 0; nf < 4; ++nf) {
        alv[nf] = al[cbase + nf * 16 + rlo];
        arv[nf] = ar[cbase + nf * 16 + rlo];
    }

#pragma unroll
    for (int mf = 0; mf < 4; ++mf) {
#pragma unroll
        for (int reg = 0; reg < 4; ++reg) {
            int r = m0 + mf * 16 + q * 4 + reg;
            float pl = 0.f, pr = 0.f;
#pragma unroll
            for (int nf = 0; nf < 4; ++nf) {
                pl += acc[mf][nf][reg] * alv[nf];
                pr += acc[mf][nf][reg] * arv[nf];
            }
#pragma unroll
            for (int off = 1; off < 16; off <<= 1) {
                pl += __shfl_xor(pl, off);
                pr += __shfl_xor(pr, off);
            }
            if (rlo == 0 && r < M) {
                el[(size_t)r * 4 + wid] = pl;
                er[(size_t)r * 4 + wid] = pr;
            }
            if (r < M) {
                us4 o = {f2bf(acc[mf][0][reg]), f2bf(acc[mf][1][reg]),
                         f2bf(acc[mf][2][reg]), f2bf(acc[mf][3][reg])};
                *(us4*)(outb + (size_t)r * 256 + cbase + rlo * 4) = o;  // permuted slots
            }
        }
    }
}

template<bool A_F32>
__global__ __launch_bounds__(256) void gemm_l12(const void* __restrict__ Av,
                                                const unsigned short* __restrict__ Wt,
                                                unsigned short* __restrict__ outb,
                                                const float* __restrict__ al,
                                                const float* __restrict__ ar,
                                                float* __restrict__ el,
                                                float* __restrict__ er, int M, int K) {
    gemm_l12_body<A_F32>(blockIdx.x, Av, Wt, outb, al, ar, el, er, M, K);
}

// ---------------- fused layer-1 GEMM + degree histogram (independent block ranges) -------
// hist is fire-and-forget atomics (latency-tolerant) -> overlaps under the GEMM blocks.
__global__ __launch_bounds__(256) void gemm1_hist(const float* __restrict__ x,
                                                  const unsigned short* __restrict__ W1t,
                                                  unsigned short* __restrict__ featb,
                                                  const float* __restrict__ al,
                                                  const float* __restrict__ ar,
                                                  float* __restrict__ el,
                                                  float* __restrict__ er,
                                                  int M, int K, int gemm_blocks,
                                                  const int* __restrict__ dst,
                                                  int* __restrict__ counts, int E) {
    int b = blockIdx.x;
    if (b < gemm_blocks) {
        gemm_l12_body<true>(b, x, W1t, featb, al, ar, el, er, M, K);
    } else {
        int i = (b - gemm_blocks) * 256 + threadIdx.x;
        if (i < E) atomicAdd(&counts[dst[i]], 1);
    }
}

// ---------------- layer-3 fused GEMM: h2(perm) @ [W3 | res_W3] ---------------------------
__global__ __launch_bounds__(256) void gemm_l3(const unsigned short* __restrict__ A,
                                               const unsigned short* __restrict__ Wt,
                                               unsigned short* __restrict__ featb,
                                               float* __restrict__ resf,
                                               const float* __restrict__ al,
                                               const float* __restrict__ ar,
                                               float* __restrict__ el,
                                               float* __restrict__ er, int M) {
    const int K = 256;
    const int lane = threadIdx.x & 63;
    const int wid = threadIdx.x >> 6;
    const int rlo = lane & 15;
    const int q = lane >> 4;
    const int kg = q * 8;
    const int m0 = blockIdx.x * 128 + (wid >> 1) * 64;
    const int ch = wid & 1;
    const int cbase = ch * 64;

    f32x4 acc[4][4];
#pragma unroll
    for (int mf = 0; mf < 4; ++mf)
#pragma unroll
        for (int nf = 0; nf < 4; ++nf) acc[mf][nf] = (f32x4){0.f, 0.f, 0.f, 0.f};

    for (int k0 = 0; k0 < K; k0 += 32) {
        short8 a[4];
#pragma unroll
        for (int mf = 0; mf < 4; ++mf) {
            int r = m0 + mf * 16 + rlo;
            if (r >= M) r = M - 1;
            a[mf] = *(const short8*)(A + (size_t)r * K + k0 + kg);
        }
#pragma unroll
        for (int nf = 0; nf < 4; ++nf) {
            short8 b = *(const short8*)(Wt + (size_t)(cbase + nf * 16 + rlo) * K + k0 + kg);
#pragma unroll
            for (int mf = 0; mf < 4; ++mf)
                acc[mf][nf] = __builtin_amdgcn_mfma_f32_16x16x32_bf16(a[mf], b, acc[mf][nf], 0, 0, 0);
        }
    }

    float alv[4], arv[4];
    if (ch == 0) {
#pragma unroll
        for (int nf = 0; nf < 4; ++nf) {
            alv[nf] = al[nf * 16 + rlo];
            arv[nf] = ar[nf * 16 + rlo];
        }
    }

#pragma unroll
    for (int mf = 0; mf < 4; ++mf) {
#pragma unroll
        for (int reg = 0; reg < 4; ++reg) {
            int r = m0 + mf * 16 + q * 4 + reg;
            if (ch == 0) {
                float pl = 0.f, pr = 0.f;
#pragma unroll
                for (int nf = 0; nf < 4; ++nf) {
                    pl += acc[mf][nf][reg] * alv[nf];
                    pr += acc[mf][nf][reg] * arv[nf];
                }
#pragma unroll
                for (int off = 1; off < 16; off <<= 1) {
                    pl += __shfl_xor(pl, off);
                    pr += __shfl_xor(pr, off);
                }
                if (rlo == 0 && r < M) { el[r] = pl; er[r] = pr; }
                if (r < M) {
                    us4 o = {f2bf(acc[mf][0][reg]), f2bf(acc[mf][1][reg]),
                             f2bf(acc[mf][2][reg]), f2bf(acc[mf][3][reg])};
                    *(us4*)(featb + (size_t)r * 64 + rlo * 4) = o;  // permuted
                }
            } else if (r < M) {
                float4 o = {acc[mf][0][reg], acc[mf][1][reg], acc[mf][2][reg], acc[mf][3][reg]};
                *(float4*)(resf + (size_t)r * 64 + rlo * 4) = o;    // permuted
            }
        }
    }
}

// ---------------- single-dispatch exclusive scan with decoupled lookback -----------------
__global__ __launch_bounds__(1024) void scan_lookback(const int* __restrict__ counts,
                                                      int* __restrict__ offsets,
                                                      int* __restrict__ cursor,
                                                      int* __restrict__ bsum,
                                                      int* __restrict__ bflag, int n, int e) {
    __shared__ int ws[16];
    __shared__ int base_s;
    int tid = threadIdx.x, lane = tid & 63, wid = tid >> 6, bid = blockIdx.x;
    int idx = bid * 1024 + tid;
    int v = (idx < n) ? counts[idx] : 0;
    int s = v;
#pragma unroll
    for (int off = 1; off < 64; off <<= 1) {
        int t = __shfl_up(s, off);
        if (lane >= off) s += t;
    }
    if (lane == 63) ws[wid] = s;
    __syncthreads();
    if (tid < 16) {
        int w2 = ws[tid];
#pragma unroll
        for (int off = 1; off < 16; off <<= 1) {
            int t = __shfl_up(w2, off);
            if (tid >= off) w2 += t;
        }
        ws[tid] = w2;
    }
    __syncthreads();
    int local_ex = (wid ? ws[wid - 1] : 0) + s - v;
    if (tid == 0) {
        __hip_atomic_store(&bsum[bid], ws[15], __ATOMIC_RELAXED, __HIP_MEMORY_SCOPE_AGENT);
        __hip_atomic_store(&bflag[bid], 1, __ATOMIC_RELEASE, __HIP_MEMORY_SCOPE_AGENT);
    }
    if (wid == 0) {
        int acc = 0;
        for (int p = lane; p < bid; p += 64) {
            while (__hip_atomic_load(&bflag[p], __ATOMIC_ACQUIRE, __HIP_MEMORY_SCOPE_AGENT) == 0) {}
            acc += __hip_atomic_load(&bsum[p], __ATOMIC_RELAXED, __HIP_MEMORY_SCOPE_AGENT);
        }
#pragma unroll
        for (int off = 32; off > 0; off >>= 1) acc += __shfl_xor(acc, off);
        if (lane == 0) base_s = acc;
    }
    __syncthreads();
    int val = base_s + local_ex;
    if (idx < n) {
        offsets[idx] = val;
        cursor[idx] = val;
    }
    if (idx == 0) offsets[n] = e;
}

// ---------------- scatter: one 8B interleaved {src,dst} store per edge -------------------
__global__ void scatter_sd(const int* __restrict__ src, const int* __restrict__ dst,
                           int* __restrict__ cursor, int2* __restrict__ csr_sd, int e) {
    int i = blockIdx.x * blockDim.x + threadIdx.x;
    if (i < e) {
        int d = dst[i];
        int pos = atomicAdd(&cursor[d], 1);
        csr_sd[pos] = make_int2(src[i], d);
    }
}

// ---------------- edge-parallel score precompute (head-major w) --------------------------
template<int H>
__global__ __launch_bounds__(256) void edge_scores(const int2* __restrict__ csr_sd,
                                                   const float* __restrict__ el,
                                                   const float* __restrict__ er,
                                                   float* __restrict__ w, int E) {
    int e4 = (blockIdx.x * 256 + threadIdx.x) * 4;
    if (e4 >= E) return;
    i32x4 p0 = *(const i32x4*)(csr_sd + e4);       // edges e4, e4+1: {s,d,s,d}
    i32x4 p1 = *(const i32x4*)(csr_sd + e4 + 2);   // edges e4+2, e4+3
    int s[4] = {p0[0], p0[2], p1[0], p1[2]};
    int d[4] = {p0[1], p0[3], p1[1], p1[3]};
    if (H == 4) {
        float4 o0, o1, o2, o3;
        float* op[4] = {&o0.x, &o1.x, &o2.x, &o3.x};
#pragma unroll
        for (int j = 0; j < 4; ++j) {
            float4 l = *(const float4*)(el + (size_t)s[j] * 4);
            float4 r = *(const float4*)(er + (size_t)d[j] * 4);
            op[0][j] = __expf(fminf(leakyf(l.x + r.x), 80.f));
            op[1][j] = __expf(fminf(leakyf(l.y + r.y), 80.f));
            op[2][j] = __expf(fminf(leakyf(l.z + r.z), 80.f));
            op[3][j] = __expf(fminf(leakyf(l.w + r.w), 80.f));
        }
        *(float4*)(w + 0 * (size_t)E + e4) = o0;
        *(float4*)(w + 1 * (size_t)E + e4) = o1;
        *(float4*)(w + 2 * (size_t)E + e4) = o2;
        *(float4*)(w + 3 * (size_t)E + e4) = o3;
    } else {
        float4 o;
#pragma unroll
        for (int j = 0; j < 4; ++j)
            (&o.x)[j] = __expf(fminf(leakyf(el[s[j]] + er[d[j]]), 80.f));
        *(float4*)(w + e4) = o;
    }
}

// ---------------- H=4 aggregate: 2 nodes per wave, 16B/lane gathers ----------------------
template<int RES, int ACT>
__global__ __launch_bounds__(256) void gat_agg4(const unsigned short* __restrict__ fp,
                                                const float* __restrict__ wbuf,
                                                const int* __restrict__ offsets,
                                                const int2* __restrict__ csr_sd,
                                                const unsigned short* __restrict__ resid,
                                                unsigned short* __restrict__ outb,
                                                int n, int E) {
    int wv = threadIdx.x >> 6;
    int lane = threadIdx.x & 63;
    int half = lane >> 5;
    int sub = lane & 31;
    int node = blockIdx.x * 8 + wv * 2 + half;

    int e0 = 0, e1 = 0;
    if (node < n) { e0 = offsets[node]; e1 = offsets[node + 1]; }
    int cnt = e1 - e0;
    int ocnt = __shfl_xor(cnt, 32);
    int mc = cnt > ocnt ? cnt : ocnt;

    const float* wb = wbuf + (size_t)(sub >> 3) * E;

    float den = 0.f;
    float acc[8] = {0.f, 0.f, 0.f, 0.f, 0.f, 0.f, 0.f, 0.f};

    for (int t = 0; t < mc; t += 8) {
        i32x4 p0, p1, p2, p3;
        f32x4 wv0, wv1;
        __builtin_memcpy(&p0, csr_sd + e0 + t, 16);        // edges t,t+1 {s,d,s,d}
        __builtin_memcpy(&p1, csr_sd + e0 + t + 2, 16);
        __builtin_memcpy(&p2, csr_sd + e0 + t + 4, 16);
        __builtin_memcpy(&p3, csr_sd + e0 + t + 6, 16);
        __builtin_memcpy(&wv0, wb + e0 + t, 16);
        __builtin_memcpy(&wv1, wb + e0 + t + 4, 16);
        int sr[8] = {p0[0], p0[2], p1[0], p1[2], p2[0], p2[2], p3[0], p3[2]};
        int s[8];
        float w[8];
#pragma unroll
        for (int j = 0; j < 8; ++j) {
            bool ok = (t + j) < cnt;
            float wj = (j < 4) ? wv0[j] : wv1[j - 4];
            s[j] = ok ? sr[j] : 0;
            w[j] = ok ? wj : 0.f;
        }
        uint4 u[8];
#pragma unroll
        for (int j = 0; j < 8; ++j)
            u[j] = *(const uint4*)(fp + (size_t)s[j] * 256 + sub * 8);
#pragma unroll
        for (int j = 0; j < 8; ++j) {
            den += w[j];
            acc[0] += w[j] * bflo(u[j].x);
            acc[1] += w[j] * bfhi(u[j].x);
            acc[2] += w[j] * bflo(u[j].y);
            acc[3] += w[j] * bfhi(u[j].y);
            acc[4] += w[j] * bflo(u[j].z);
            acc[5] += w[j] * bfhi(u[j].z);
            acc[6] += w[j] * bflo(u[j].w);
            acc[7] += w[j] * bfhi(u[j].w);
        }
    }

    if (node >= n) return;

    float inv = den > 0.f ? 1.f / den : 0.f;
    float v[8];
#pragma unroll
    for (int i = 0; i < 8; ++i) v[i] = acc[i] * inv;

    if (RES == 1) {
        uint4 ru = *(const uint4*)(resid + (size_t)node * 256 + sub * 8);
        v[0] += bflo(ru.x); v[1] += bfhi(ru.x);
        v[2] += bflo(ru.y); v[3] += bfhi(ru.y);
        v[4] += bflo(ru.z); v[5] += bfhi(ru.z);
        v[6] += bflo(ru.w); v[7] += bfhi(ru.w);
    }
    if (ACT == 1) {
#pragma unroll
        for (int i = 0; i < 8; ++i) v[i] = v[i] > 0.f ? v[i] : __expf(v[i]) - 1.f;
    }
    uint4 o;
    o.x = (unsigned)f2bf(v[0]) | ((unsigned)f2bf(v[1]) << 16);
    o.y = (unsigned)f2bf(v[2]) | ((unsigned)f2bf(v[3]) << 16);
    o.z = (unsigned)f2bf(v[4]) | ((unsigned)f2bf(v[5]) << 16);
    o.w = (unsigned)f2bf(v[6]) | ((unsigned)f2bf(v[7]) << 16);
    *(uint4*)(outb + (size_t)node * 256 + sub * 8) = o;
}

// ---------------- H=1 aggregate: 4 nodes per wave, 8B/lane gathers -----------------------
__global__ __launch_bounds__(256) void gat_agg1(const unsigned short* __restrict__ fp,
                                                const float* __restrict__ wbuf,
                                                const int* __restrict__ offsets,
                                                const int2* __restrict__ csr_sd,
                                                const float* __restrict__ resf,
                                                float* __restrict__ outv, int n, int E) {
    int wv = threadIdx.x >> 6;
    int lane = threadIdx.x & 63;
    int sub = lane & 15;
    int node = blockIdx.x * 16 + wv * 4 + (lane >> 4);

    int e0 = 0, e1 = 0;
    if (node < n) { e0 = offsets[node]; e1 = offsets[node + 1]; }
    int cnt = e1 - e0;
    int m1 = __shfl_xor(cnt, 16);
    int mc = cnt > m1 ? cnt : m1;
    int m2 = __shfl_xor(mc, 32);
    mc = mc > m2 ? mc : m2;

    float den = 0.f;
    float acc[4] = {0.f, 0.f, 0.f, 0.f};

    for (int t = 0; t < mc; t += 8) {
        i32x4 p0, p1, p2, p3;
        f32x4 wv0, wv1;
        __builtin_memcpy(&p0, csr_sd + e0 + t, 16);
        __builtin_memcpy(&p1, csr_sd + e0 + t + 2, 16);
        __builtin_memcpy(&p2, csr_sd + e0 + t + 4, 16);
        __builtin_memcpy(&p3, csr_sd + e0 + t + 6, 16);
        __builtin_memcpy(&wv0, wbuf + e0 + t, 16);
        __builtin_memcpy(&wv1, wbuf + e0 + t + 4, 16);
        int sr[8] = {p0[0], p0[2], p1[0], p1[2], p2[0], p2[2], p3[0], p3[2]};
        int s[8];
        float w[8];
#pragma unroll
        for (int j = 0; j < 8; ++j) {
            bool ok = (t + j) < cnt;
            float wj = (j < 4) ? wv0[j] : wv1[j - 4];
            s[j] = ok ? sr[j] : 0;
            w[j] = ok ? wj : 0.f;
        }
        uint2 u[8];
#pragma unroll
        for (int j = 0; j < 8; ++j)
            u[j] = *(const uint2*)(fp + (size_t)s[j] * 64 + sub * 4);
#pragma unroll
        for (int j = 0; j < 8; ++j) {
            den += w[j];
            acc[0] += w[j] * bflo(u[j].x);
            acc[1] += w[j] * bfhi(u[j].x);
            acc[2] += w[j] * bflo(u[j].y);
            acc[3] += w[j] * bfhi(u[j].y);
        }
    }

    if (node >= n) return;

    float inv = den > 0.f ? 1.f / den : 0.f;
    float4 rv = *(const float4*)(resf + (size_t)node * 64 + sub * 4);
    float v[4];
    v[0] = acc[0] * inv + rv.x;
    v[1] = acc[1] * inv + rv.y;
    v[2] = acc[2] * inv + rv.z;
    v[3] = acc[3] * inv + rv.w;

#pragma unroll
    for (int i = 0; i < 4; ++i) {
        int p = sub * 4 + i;                 // permuted slot
        int c = (p & 3) * 16 + (p >> 2);     // true column
        outv[(size_t)node * 64 + c] = v[i];
    }
}

// ---------------- launcher ----------------------------------------------------------------
extern "C" void kernel_launch(void* const* d_in, const int* in_sizes, int n_in,
                              void* d_out, int out_size, void* d_ws, size_t ws_size,
                              hipStream_t stream) {
    const float* x      = (const float*)d_in[0];
    const float* W1     = (const float*)d_in[1];
    const float* al1    = (const float*)d_in[2];
    const float* ar1    = (const float*)d_in[3];
    const float* W2     = (const float*)d_in[4];
    const float* al2    = (const float*)d_in[5];
    const float* ar2    = (const float*)d_in[6];
    const float* W3     = (const float*)d_in[7];
    const float* al3    = (const float*)d_in[8];
    const float* ar3    = (const float*)d_in[9];
    const float* res_W3 = (const float*)d_in[10];
    const int*   src    = (const int*)d_in[11];
    const int*   dst    = (const int*)d_in[12];

    const int N = in_sizes[0] / 128;    // 50000
    const int E = in_sizes[11];         // 500000

    float* out = (float*)d_out;

    // workspace layout (16B alignment maintained)
    unsigned short* featb = (unsigned short*)d_ws;          // [N,256] (layer3: [N,64])
    unsigned short* h1    = featb + (size_t)N * 256;        // [N,256]
    unsigned short* h2    = h1 + (size_t)N * 256;           // [N,256]
    unsigned short* W1t   = h2 + (size_t)N * 256;           // [256,128]
    unsigned short* W2t   = W1t + 256 * 128;                // [256,256]
    unsigned short* W3c   = W2t + 256 * 256;                // [128,256] = [W3t | RW3t]
    float* resf = (float*)(W3c + 128 * 256);                // [N,64]
    float* el   = resf + (size_t)N * 64;                    // [N,4]
    float* er   = el + (size_t)N * 4;                       // [N,4]
    float* wbuf = er + (size_t)N * 4;                       // [4][E] head-major
    int* offsets = (int*)(wbuf + (size_t)E * 4);            // [N+1] (padded)
    int* cursor  = offsets + (N + 8);                       // [N]
    int2* csr_sd = (int2*)(cursor + N);                     // [E] {src,dst} + pad
    int* bsums   = (int*)(csr_sd + E + 32);                 // [64]
    int* bflag   = bsums + 64;                              // [64]

    const int T = 256;
    const int scan_blocks = (N + 1023) / 1024;              // 49 (co-resident on 256 CUs)
    const int edge_blocks = (E + T - 1) / T;                // 1954
    const int zero_blocks = (N + 255) / 256;                // 196
    const int es_blocks = (E / 4 + T - 1) / T;              // 489

    int gemm12_blocks = (N + 63) / 64;                      // 782
    int gemm3_blocks = (N + 127) / 128;                     // 391
    int agg4_blocks = (N + 7) / 8;                          // 6250
    int agg1_blocks = (N + 15) / 16;                        // 3125

    // ---- 1: prep (weights + zero counts + zero flags) ----
    prep<<<512 + zero_blocks, T, 0, stream>>>(W1, W2, W3, res_W3, W1t, W2t, W3c, cursor, bflag, N);
    // ---- 2: layer-1 GEMM (+el/er) fused with degree histogram ----
    gemm1_hist<<<gemm12_blocks + edge_blocks, T, 0, stream>>>(x, W1t, featb, al1, ar1, el, er,
                                                              N, 128, gemm12_blocks, dst, cursor, E);
    // ---- 3: single-dispatch scan (offsets + cursor) ----
    scan_lookback<<<scan_blocks, 1024, 0, stream>>>(cursor, offsets, cursor, bsums, bflag, N, E);
    // ---- 4: scatter (interleaved {src,dst}, one 8B store per edge) ----
    scatter_sd<<<edge_blocks, T, 0, stream>>>(src, dst, cursor, csr_sd, E);
    // ---- 5-6: layer-1 scores + aggregate ----
    edge_scores<4><<<es_blocks, T, 0, stream>>>(csr_sd, el, er, wbuf, E);
    gat_agg4<0, 1><<<agg4_blocks, T, 0, stream>>>(featb, wbuf, offsets, csr_sd, nullptr, h1, N, E);
    // ---- 7-9: layer 2 ----
    gemm_l12<false><<<gemm12_blocks, T, 0, stream>>>(h1, W2t, featb, al2, ar2, el, er, N, 256);
    edge_scores<4><<<es_blocks, T, 0, stream>>>(csr_sd, el, er, wbuf, E);
    gat_agg4<1, 1><<<agg4_blocks, T, 0, stream>>>(featb, wbuf, offsets, csr_sd, h1, h2, N, E);
    // ---- 10-12: layer 3 ----
    gemm_l3<<<gemm3_blocks, T, 0, stream>>>(h2, W3c, featb, resf, al3, ar3, el, er, N);
    edge_scores<1><<<es_blocks, T, 0, stream>>>(csr_sd, el, er, wbuf, E);
    gat_agg1<<<agg1_blocks, T, 0, stream>>>(featb, wbuf, offsets, csr_sd, resf, out, N, E);
}